// Round 12
// baseline (281.984 us; speedup 1.0000x reference)
//
#include <hip/hip_runtime.h>
#include <stdint.h>

#define EPS 1e-5f
#define LOG2E 1.4426950408889634f

// ---------------- problem constants ----------------
#define NPTS 80000
#define CDIM 128
#define ODIM 64
#define KNBR 8
#define MSUP 1000

// ---------------- workspace layout (bytes) ----------------
#define KP2H_OFF 0                 // [1000][128] bf16 = 256 KB (BN1-folded k+pe table)
#define UT_OFF   (256*1024)        // [1000][64]  f32  = 256 KB (scaled by LOG2E)
#define WQF_OFF  (512*1024)        // 32 frags * 1KB = 32 KB (Wq*s1c, A-layout)
#define W1F_OFF  (544*1024)        // 16 frags * 1KB = 16 KB (W1*s2c, A-layout)
#define W2F_OFF  (560*1024)        // 8 frags * 1KB  = 8 KB  (W2*LOG2E, B-layout)
#define C1_OFF   (568*1024)        // [64] f32 ((b1-m2)*s2c + beta2)
#define QSG_OFF  (576*1024)        // [80000][128] bf16 = 20.48 MB (q projection)
#define WSTAGE_BYTES (16*1024 + 8*1024 + 256)   // 24832 (W1F..C1 contiguous blob)

typedef float f32x4 __attribute__((ext_vector_type(4)));
typedef short bf16x8 __attribute__((ext_vector_type(8)));
typedef __bf16 bf16v8 __attribute__((ext_vector_type(8)));
typedef __bf16 bf16v4 __attribute__((ext_vector_type(4)));

union FragU { bf16x8 v; unsigned u[4]; uint4 q; };

#if __has_builtin(__builtin_amdgcn_cvt_pk_bf16_f32)
#define HAVE_PK_BF16 1
#endif

__device__ inline unsigned pk_bf16(float lo, float hi) {
#ifdef HAVE_PK_BF16
  typedef __bf16 bf16x2_t __attribute__((ext_vector_type(2)));
  return __builtin_bit_cast(unsigned, __builtin_amdgcn_cvt_pk_bf16_f32(lo, hi));
#else
  unsigned a = __builtin_bit_cast(unsigned, lo);
  unsigned b = __builtin_bit_cast(unsigned, hi);
  a += 0x7FFFu + ((a >> 16) & 1u);
  b += 0x7FFFu + ((b >> 16) & 1u);
  return (a >> 16) | (b & 0xFFFF0000u);
#endif
}

__device__ inline float exp2_fast(float x) {
#if __has_builtin(__builtin_amdgcn_exp2f)
  return __builtin_amdgcn_exp2f(x);
#else
  return exp2f(x);
#endif
}

// ============================================================
// Kernel 1 (prep): blocks 0..999 per-superpoint tables; 1000..1014 weight swizzle.
// uT pre-scaled by LOG2E; W2 frags pre-scaled by LOG2E (exp->exp2 rebase).
// ============================================================
__global__ __launch_bounds__(256)
void k_prep(const float* __restrict__ sp_fea, const float* __restrict__ sp_xyz,
            const float* __restrict__ Wk, const float* __restrict__ bk,
            const float* __restrict__ Wv, const float* __restrict__ bv,
            const float* __restrict__ Wp1, const float* __restrict__ bp1,
            const float* __restrict__ gp, const float* __restrict__ betap,
            const float* __restrict__ mp, const float* __restrict__ vp,
            const float* __restrict__ Wp2, const float* __restrict__ bp2,
            const float* __restrict__ g1, const float* __restrict__ beta1,
            const float* __restrict__ m1, const float* __restrict__ v1,
            const float* __restrict__ bq,
            const float* __restrict__ Wq, const float* __restrict__ W1,
            const float* __restrict__ W2,
            const float* __restrict__ g2, const float* __restrict__ v2,
            const float* __restrict__ b1, const float* __restrict__ m2,
            const float* __restrict__ beta2, char* __restrict__ ws)
{
  if (blockIdx.x < 1000) {
    unsigned short* kp2h = (unsigned short*)(ws + KP2H_OFF);
    float* uT = (float*)(ws + UT_OFF);
    const int m = blockIdx.x;
    const int t = threadIdx.x;
    const int c = t & 127, half = t >> 7;
    __shared__ float fea[128];
    __shared__ float pk[128], pv[128];
    if (t < 128) fea[t] = sp_fea[m * 128 + t];
    __syncthreads();
    float kv = 0.f, vv = 0.f;
    const float* wkc = Wk + half * 64 * 128 + c;
    const float* wvc = Wv + half * 64 * 128 + c;
    const float* feah = fea + half * 64;
    #pragma unroll 8
    for (int d = 0; d < 64; ++d) {
      const float f = feah[d];
      kv = fmaf(f, wkc[d * 128], kv);
      vv = fmaf(f, wvc[d * 128], vv);
    }
    if (half) { pk[c] = kv; pv[c] = vv; }
    __syncthreads();
    if (!half) {
      kv += pk[c] + bk[c];
      vv += pv[c] + bv[c];
      const float x0 = sp_xyz[m*3+0], x1 = sp_xyz[m*3+1], x2 = sp_xyz[m*3+2];
      float pe = bp2[c];
      #pragma unroll
      for (int ii = 0; ii < 3; ++ii) {
        float s = bp1[ii] + x0*Wp1[0*3+ii] + x1*Wp1[1*3+ii] + x2*Wp1[2*3+ii];
        s = (s - mp[ii]) * (gp[ii] * rsqrtf(vp[ii] + EPS)) + betap[ii];
        s = fmaxf(s, 0.0f);
        pe += s * Wp2[ii*128 + c];
      }
      const float s1c = g1[c] * rsqrtf(v1[c] + EPS);
      const float kpv = (kv + pe - m1[c] - bq[c]) * s1c + beta1[c];
      kp2h[m*128 + c] = (unsigned short)(pk_bf16(kpv, kpv) & 0xFFFFu);
      pv[c] = vv + pe;          // reuse pv as (v+pe) storage
    }
    __syncthreads();
    if (t < 64) uT[m*64 + t] = (pv[t] + pv[t + 64]) * LOG2E;
  } else {
    const int tid = (blockIdx.x - 1000) * 256 + threadIdx.x;
    if (tid < 2048) {
      // Wqf^T A-frags: frag f = kt*8+mt ; A[m=c][k=d], Wqf[d][c]=Wq[d][c]*s1c[c]
      const int e = tid, f = e >> 6, l = e & 63;
      const int kt = f >> 3, mt = f & 7;
      const int c = mt*16 + (l & 15);
      const int d0 = kt*32 + (l >> 4)*8;
      const float sc = g1[c] * rsqrtf(v1[c] + EPS);
      uint4 u;
      u.x = pk_bf16(Wq[(d0+0)*128 + c]*sc, Wq[(d0+1)*128 + c]*sc);
      u.y = pk_bf16(Wq[(d0+2)*128 + c]*sc, Wq[(d0+3)*128 + c]*sc);
      u.z = pk_bf16(Wq[(d0+4)*128 + c]*sc, Wq[(d0+5)*128 + c]*sc);
      u.w = pk_bf16(Wq[(d0+6)*128 + c]*sc, Wq[(d0+7)*128 + c]*sc);
      *(uint4*)(ws + WQF_OFF + e*16) = u;
    } else if (tid < 3072) {
      // W1f^T A-frags: frag f = kt*4+jt ; A[m=j][k=c], W1f[c][j]=W1[c][j]*s2c[j]
      const int e = tid - 2048, f = e >> 6, l = e & 63;
      const int kt = f >> 2, jt = f & 3;
      const int j = jt*16 + (l & 15);
      const int c0 = kt*32 + (l >> 4)*8;
      const float sc = g2[j] * rsqrtf(v2[j] + EPS);
      uint4 u;
      u.x = pk_bf16(W1[(c0+0)*64 + j]*sc, W1[(c0+1)*64 + j]*sc);
      u.y = pk_bf16(W1[(c0+2)*64 + j]*sc, W1[(c0+3)*64 + j]*sc);
      u.z = pk_bf16(W1[(c0+4)*64 + j]*sc, W1[(c0+5)*64 + j]*sc);
      u.w = pk_bf16(W1[(c0+6)*64 + j]*sc, W1[(c0+7)*64 + j]*sc);
      *(uint4*)(ws + W1F_OFF + e*16) = u;
    } else if (tid < 3584) {
      // W2 B-frags scaled by LOG2E: frag f = kt2*4+nt ; B[k=j][n=j']
      const int e = tid - 3072, f = e >> 6, l = e & 63;
      const int kt2 = f >> 2, nt = f & 3;
      const int jp = nt*16 + (l & 15);
      const int j0 = kt2*32 + (l >> 4)*8;
      uint4 u;
      u.x = pk_bf16(W2[(j0+0)*64 + jp]*LOG2E, W2[(j0+1)*64 + jp]*LOG2E);
      u.y = pk_bf16(W2[(j0+2)*64 + jp]*LOG2E, W2[(j0+3)*64 + jp]*LOG2E);
      u.z = pk_bf16(W2[(j0+4)*64 + jp]*LOG2E, W2[(j0+5)*64 + jp]*LOG2E);
      u.w = pk_bf16(W2[(j0+6)*64 + jp]*LOG2E, W2[(j0+7)*64 + jp]*LOG2E);
      *(uint4*)(ws + W2F_OFF + e*16) = u;
    } else if (tid < 3648) {
      const int j = tid - 3584;
      const float sc = g2[j] * rsqrtf(v2[j] + EPS);
      ((float*)(ws + C1_OFF))[j] = (b1[j] - m2[j]) * sc + beta2[j];
    }
  }
}

// ============================================================
// Kernel 2: streaming q-projection (grid 1250, Wqf in LDS).
// ============================================================
__global__ __launch_bounds__(256, 4)
void k_q(const float* __restrict__ o_p_fea, char* __restrict__ ws)
{
  __shared__ __align__(16) char ldsq[32*1024];
  char* qs_g = ws + QSG_OFF;
  const int t = threadIdx.x;
  const int wave = t >> 6, l = t & 63;
  const int quad = l >> 4, row = l & 15;
  const int n0 = (blockIdx.x * 4 + wave) * 16;

  {
    const uint4* src = (const uint4*)(ws + WQF_OFF);
    uint4* dst = (uint4*)ldsq;
    #pragma unroll
    for (int i = 0; i < 8; ++i) dst[t + i*256] = src[t + i*256];
  }
  __syncthreads();

  f32x4 qa[8];
  #pragma unroll
  for (int mt = 0; mt < 8; ++mt) qa[mt] = (f32x4){0.f, 0.f, 0.f, 0.f};
  const float* feab = o_p_fea + (size_t)(n0 + row) * 128;
  #pragma unroll
  for (int kt = 0; kt < 4; ++kt) {
    f32x4 fa = *(const f32x4*)(feab + kt*32 + quad*8);
    f32x4 fb = *(const f32x4*)(feab + kt*32 + quad*8 + 4);
    FragU bu;
    bu.u[0] = pk_bf16(fa[0], fa[1]);
    bu.u[1] = pk_bf16(fa[2], fa[3]);
    bu.u[2] = pk_bf16(fb[0], fb[1]);
    bu.u[3] = pk_bf16(fb[2], fb[3]);
    #pragma unroll
    for (int mt = 0; mt < 8; ++mt) {
      const bf16x8 wf = *(const bf16x8*)(ldsq + ((kt*8+mt)*64 + l)*16);
      qa[mt] = __builtin_amdgcn_mfma_f32_16x16x32_bf16(wf, bu.v, qa[mt], 0, 0, 0);
    }
  }
  #pragma unroll
  for (int mt = 0; mt < 8; ++mt) {
    uint2 pp;
    pp.x = pk_bf16(qa[mt][0], qa[mt][1]);
    pp.y = pk_bf16(qa[mt][2], qa[mt][3]);
    *(uint2*)(qs_g + (size_t)(n0 + row) * 256 + mt*32 + quad*8) = pp;
  }
}

// ============================================================
// Kernel 3: fused main. r11 body (flattened mapping + epilogue software
// pipeline) with the occupancy target FIXED via amdgpu_waves_per_eu(3,4).
// r6/r11 post-mortems: the compiler's occupancy heuristic targeted 8 resp.
// 6 waves/SIMD (VGPR 64 resp. 84 = 512/8, 512/6) and SPILLED the pipeline
// state rather than exceed its own target -- launch_bounds' min-waves arg
// only floors the target. waves_per_eu(3,4) caps the target at 4 waves/SIMD
// (= the LDS-set static occupancy anyway), freeing the allocator to hold
// EpiState (~117 VGPR) in registers.
// TRIPWIRE: VGPR must rise >100 and WRITE_SIZE stay ~2.5 MB, else revert.
// ============================================================
#define H2_PITCH 144               // bytes/row (72 bf16; 16B-aligned rows)
#define H2_SIZE  (16*144)          // 2304 B / wave
#define W1L_OFF  0
#define W2L_OFF  (16*1024)
#define C1L_OFF  (24*1024)
#define H2_BASE  24832
#define LDS_TOTAL (H2_BASE + 4*H2_SIZE)   // 34048

struct EpiState { f32x4 a2[4]; float u4[4][4]; };

__device__ __forceinline__ void epilogue(const EpiState& st, const float* b2r,
                                         int quad, int row,
                                         float* __restrict__ out, int base,
                                         bool wr)
{
  // lane holds s2'[r'=quad*4+reg][j'=row+16*nt] (pre-scaled by LOG2E);
  // softmax over 8 rows/point: in-reg 4 + shfl_xor(16) partner quad.
  float e[4][4], rs[4];
  #pragma unroll
  for (int nt = 0; nt < 4; ++nt) {
    #pragma unroll
    for (int rg = 0; rg < 4; ++rg) e[nt][rg] = exp2_fast(st.a2[nt][rg] + b2r[nt]);
    float s = e[nt][0] + e[nt][1] + e[nt][2] + e[nt][3];
    s += __shfl_xor(s, 16);
    rs[nt] = __builtin_amdgcn_rcpf(s);
  }
  // bi[r'] = sum_j' w[r'][j'] * uT[m(r')][j']  (uT pre-scaled by LOG2E)
  float bi[4] = {0.f, 0.f, 0.f, 0.f};
  #pragma unroll
  for (int rg = 0; rg < 4; ++rg) {
    #pragma unroll
    for (int nt = 0; nt < 4; ++nt)
      bi[rg] = fmaf(e[nt][rg] * rs[nt], st.u4[rg][nt], bi[rg]);
  }
  #pragma unroll
  for (int rg = 0; rg < 4; ++rg) {
    float b = bi[rg];
    b += __shfl_xor(b, 1);
    b += __shfl_xor(b, 2);
    b += __shfl_xor(b, 4);
    b += __shfl_xor(b, 8);
    bi[rg] = b;
  }
  const float eb0 = exp2_fast(bi[0]), eb1 = exp2_fast(bi[1]);
  const float eb2 = exp2_fast(bi[2]), eb3 = exp2_fast(bi[3]);
  float sb = eb0 + eb1 + eb2 + eb3;
  sb += __shfl_xor(sb, 16);
  const float rsb = __builtin_amdgcn_rcpf(sb);
  if (wr && row < 4) {
    const float vsel = row == 0 ? eb0 : row == 1 ? eb1 : row == 2 ? eb2 : eb3;
    out[base + quad*4 + row] = vsel * rsb;
  }
}

__global__ __launch_bounds__(256)
__attribute__((amdgpu_waves_per_eu(3, 4)))
void k_main(const int* __restrict__ idx, const float* __restrict__ b2,
            const char* __restrict__ ws, float* __restrict__ out)
{
  const unsigned short* kp2h = (const unsigned short*)(ws + KP2H_OFF);
  const float* uT = (const float*)(ws + UT_OFF);
  const char* qs_g = ws + QSG_OFF;

  __shared__ __align__(16) char lds[LDS_TOTAL];
  const int t = threadIdx.x;
  const int wave = t >> 6, l = t & 63;
  const int quad = l >> 4, row = l & 15;
  char* h2_w = lds + H2_BASE + wave * H2_SIZE;

  const int slot = blockIdx.x * 4 + wave;   // 0..9999 wave-slots
  const int gid0 = slot * 4;                // 4 group-tasks per wave
  const int nloc = row >> 3;

  // ---- stage weight fragments into block-shared LDS (24832 B) ----
  {
    const uint4* src = (const uint4*)(ws + W1F_OFF);
    uint4* dst = (uint4*)lds;
    #pragma unroll
    for (int i = 0; i < 7; ++i) {
      const int e = t + i * 256;
      if (e < WSTAGE_BYTES / 16) dst[e] = src[e];
    }
  }

  // prefetch this wave's 4 groups' gather indices (row pattern for kp2h)
  int mr4[4];
  #pragma unroll
  for (int g = 0; g < 4; ++g) mr4[g] = idx[(gid0 + g)*16 + row];

  __syncthreads();   // weights staged

  f32x4 c1r[4];
  #pragma unroll
  for (int jt = 0; jt < 4; ++jt)
    c1r[jt] = *(const f32x4*)(lds + C1L_OFF + (jt*16 + quad*4)*4);
  float b2r[4];
  #pragma unroll
  for (int nt = 0; nt < 4; ++nt) b2r[nt] = b2[row + nt*16] * LOG2E;

  // ---- group-0 staging: idx (quad pattern), kp2h row, qs row ----
  int msc[4];
  #pragma unroll
  for (int rg = 0; rg < 4; ++rg) msc[rg] = idx[gid0*16 + quad*4 + rg];
  uint4 kfc[4], qpc[4];
  {
    const uint4* kr = (const uint4*)(kp2h + (size_t)mr4[0] * 128);
    const uint4* qr = (const uint4*)(qs_g + (size_t)(gid0*2 + nloc) * 256);
    #pragma unroll
    for (int kt = 0; kt < 4; ++kt) { kfc[kt] = kr[kt*4 + quad]; qpc[kt] = qr[kt*4 + quad]; }
  }

  EpiState st;   // pipelined epilogue state (group g-1)
  #pragma unroll
  for (int nt = 0; nt < 4; ++nt) {
    st.a2[nt] = (f32x4){0.f, 0.f, 0.f, 0.f};
    #pragma unroll
    for (int rg = 0; rg < 4; ++rg) st.u4[nt][rg] = 0.f;
  }

  #pragma unroll 1
  for (int g = 0; g < 4; ++g) {
    const int gid = gid0 + g;
    // prefetch next group's operands (address-known; land during compute)
    int msn[4];
    uint4 kfn[4], qpn[4];
    if (g < 3) {
      #pragma unroll
      for (int rg = 0; rg < 4; ++rg) msn[rg] = idx[(gid+1)*16 + quad*4 + rg];
      const uint4* kr = (const uint4*)(kp2h + (size_t)mr4[g+1] * 128);
      const uint4* qr = (const uint4*)(qs_g + (size_t)((gid+1)*2 + nloc) * 256);
      #pragma unroll
      for (int kt = 0; kt < 4; ++kt) { kfn[kt] = kr[kt*4 + quad]; qpn[kt] = qr[kt*4 + quad]; }
    }
    // uT loads for THIS group; consumed by NEXT iteration's epilogue
    float u4n[4][4];
    #pragma unroll
    for (int rg = 0; rg < 4; ++rg) {
      const float* ur = uT + (size_t)msc[rg] * 64 + row;
      #pragma unroll
      for (int nt = 0; nt < 4; ++nt) u4n[rg][nt] = ur[nt*16];
    }

    // GEMM1 (transposed): h2^T = W1f^T @ X^T ; X = relu(kp2[m] - qs[n])
    f32x4 a1[4];
    #pragma unroll
    for (int jt = 0; jt < 4; ++jt) a1[jt] = (f32x4){0.f, 0.f, 0.f, 0.f};
    #pragma unroll
    for (int kt = 0; kt < 4; ++kt) {
      const bf16v8 kv = __builtin_bit_cast(bf16v8, kfc[kt]);
      const bf16v8 qv = __builtin_bit_cast(bf16v8, qpc[kt]);
      bf16v8 z = {};
      bf16v8 x = __builtin_elementwise_max((bf16v8)(kv - qv), z);
      FragU xf;
      xf.q = __builtin_bit_cast(uint4, x);
      #pragma unroll
      for (int jt = 0; jt < 4; ++jt) {
        const bf16x8 wf = *(const bf16x8*)(lds + W1L_OFF + (kt*4+jt)*1024 + l*16);
        a1[jt] = __builtin_amdgcn_mfma_f32_16x16x32_bf16(wf, xf.v, a1[jt], 0, 0, 0);
      }
    }

    // bn2-fold + pack + packed relu; D^T: n=row -> r, m=quad*4+reg+16*jt -> j
    #pragma unroll
    for (int jt = 0; jt < 4; ++jt) {
      f32x4 v = a1[jt] + c1r[jt];
      uint2 pp;
      pp.x = pk_bf16(v[0], v[1]);
      pp.y = pk_bf16(v[2], v[3]);
      bf16v4 h = __builtin_bit_cast(bf16v4, pp);
      bf16v4 z4 = {};
      h = __builtin_elementwise_max(h, z4);
      pp = __builtin_bit_cast(uint2, h);
      *(uint2*)(h2_w + row*H2_PITCH + (jt*16 + quad*4)*2) = pp;
    }

    // GEMM2: s2' = h2 @ (W2*LOG2E)
    f32x4 a2[4];
    #pragma unroll
    for (int nt = 0; nt < 4; ++nt) a2[nt] = (f32x4){0.f, 0.f, 0.f, 0.f};
    #pragma unroll
    for (int kt2 = 0; kt2 < 2; ++kt2) {
      const bf16x8 af = *(const bf16x8*)(h2_w + row*H2_PITCH + kt2*64 + quad*16);
      #pragma unroll
      for (int nt = 0; nt < 4; ++nt) {
        const bf16x8 wf = *(const bf16x8*)(lds + W2L_OFF + (kt2*4+nt)*1024 + l*16);
        a2[nt] = __builtin_amdgcn_mfma_f32_16x16x32_bf16(af, wf, a2[nt], 0, 0, 0);
      }
    }

    // pipelined epilogue for group g-1 (independent of this group's MFMA
    // chain -> scheduler interleaves shuffles/exp2 with MFMAs)
    {
      const int gm1 = gid - 1;
      const int base = (gm1 < gid0 ? gid0 : gm1) * 16;
      epilogue(st, b2r, quad, row, out, base, g > 0);
    }

    // rotate pipeline state
    #pragma unroll
    for (int nt = 0; nt < 4; ++nt) st.a2[nt] = a2[nt];
    #pragma unroll
    for (int rg = 0; rg < 4; ++rg)
      #pragma unroll
      for (int nt = 0; nt < 4; ++nt) st.u4[rg][nt] = u4n[rg][nt];
    if (g < 3) {
      #pragma unroll
      for (int rg = 0; rg < 4; ++rg) msc[rg] = msn[rg];
      #pragma unroll
      for (int kt = 0; kt < 4; ++kt) { kfc[kt] = kfn[kt]; qpc[kt] = qpn[kt]; }
    }
  }
  // drain: epilogue for the last group
  epilogue(st, b2r, quad, row, out, (gid0 + 3) * 16, true);
}

// ============================================================
extern "C" void kernel_launch(void* const* d_in, const int* in_sizes, int n_in,
                              void* d_out, int out_size, void* d_ws, size_t ws_size,
                              hipStream_t stream)
{
  const float* sp_fea  = (const float*)d_in[0];
  const float* sp_xyz  = (const float*)d_in[1];
  const float* o_p_fea = (const float*)d_in[2];
  // d_in[3] p_xyz unused by reference
  const float* Wq    = (const float*)d_in[4];
  const float* bq    = (const float*)d_in[5];
  const float* Wk    = (const float*)d_in[6];
  const float* bk    = (const float*)d_in[7];
  const float* Wv    = (const float*)d_in[8];
  const float* bv    = (const float*)d_in[9];
  const float* Wp1   = (const float*)d_in[10];
  const float* bp1   = (const float*)d_in[11];
  const float* gp    = (const float*)d_in[12];
  const float* betap = (const float*)d_in[13];
  const float* mp    = (const float*)d_in[14];
  const float* vp    = (const float*)d_in[15];
  const float* Wp2   = (const float*)d_in[16];
  const float* bp2   = (const float*)d_in[17];
  const float* g1    = (const float*)d_in[18];
  const float* beta1 = (const float*)d_in[19];
  const float* m1    = (const float*)d_in[20];
  const float* v1    = (const float*)d_in[21];
  const float* W1    = (const float*)d_in[22];
  const float* b1    = (const float*)d_in[23];
  const float* g2    = (const float*)d_in[24];
  const float* beta2 = (const float*)d_in[25];
  const float* m2    = (const float*)d_in[26];
  const float* v2    = (const float*)d_in[27];
  const float* W2    = (const float*)d_in[28];
  const float* b2    = (const float*)d_in[29];
  const int* c2p_idx_abs = (const int*)d_in[30];
  // d_in[31..34] unused by reference

  char* ws = (char*)d_ws;
  float* out = (float*)d_out;

  hipLaunchKernelGGL(k_prep, dim3(1015), dim3(256), 0, stream,
                     sp_fea, sp_xyz, Wk, bk, Wv, bv, Wp1, bp1, gp, betap, mp, vp,
                     Wp2, bp2, g1, beta1, m1, v1, bq,
                     Wq, W1, W2, g2, v2, b1, m2, beta2, ws);
  hipLaunchKernelGGL(k_q, dim3(1250), dim3(256), 0, stream,
                     o_p_fea, ws);
  hipLaunchKernelGGL(k_main, dim3(2500), dim3(256), 0, stream,
                     c2p_idx_abs, b2, ws, out);
}

// Round 13
// 215.111 us; speedup vs baseline: 1.3109x; 1.3109x over previous
//
#include <hip/hip_runtime.h>
#include <stdint.h>

#define EPS 1e-5f
#define LOG2E 1.4426950408889634f

// ---------------- problem constants ----------------
#define NPTS 80000
#define CDIM 128
#define ODIM 64
#define KNBR 8
#define MSUP 1000

// ---------------- workspace layout (bytes) ----------------
#define KP2H_OFF 0                 // [1000][128] bf16 = 256 KB (BN1-folded k+pe table)
#define UT_OFF   (256*1024)        // [1000][64]  f32  = 256 KB (scaled by LOG2E)
#define WQF_OFF  (512*1024)        // 32 frags * 1KB = 32 KB (Wq*s1c, A-layout)
#define W1F_OFF  (544*1024)        // 16 frags * 1KB = 16 KB (W1*s2c, A-layout)
#define W2F_OFF  (560*1024)        // 8 frags * 1KB  = 8 KB  (W2*LOG2E, B-layout)
#define C1_OFF   (568*1024)        // [64] f32 ((b1-m2)*s2c + beta2)
#define QSG_OFF  (576*1024)        // [80000][128] bf16 = 20.48 MB (q projection)
#define WSTAGE_BYTES (16*1024 + 8*1024 + 256)   // 24832 (W1F..C1 contiguous blob)

typedef float f32x4 __attribute__((ext_vector_type(4)));
typedef short bf16x8 __attribute__((ext_vector_type(8)));
typedef __bf16 bf16v8 __attribute__((ext_vector_type(8)));
typedef __bf16 bf16v4 __attribute__((ext_vector_type(4)));

union FragU { bf16x8 v; unsigned u[4]; uint4 q; };

#if __has_builtin(__builtin_amdgcn_cvt_pk_bf16_f32)
#define HAVE_PK_BF16 1
#endif

__device__ inline unsigned pk_bf16(float lo, float hi) {
#ifdef HAVE_PK_BF16
  typedef __bf16 bf16x2_t __attribute__((ext_vector_type(2)));
  return __builtin_bit_cast(unsigned, __builtin_amdgcn_cvt_pk_bf16_f32(lo, hi));
#else
  unsigned a = __builtin_bit_cast(unsigned, lo);
  unsigned b = __builtin_bit_cast(unsigned, hi);
  a += 0x7FFFu + ((a >> 16) & 1u);
  b += 0x7FFFu + ((b >> 16) & 1u);
  return (a >> 16) | (b & 0xFFFF0000u);
#endif
}

__device__ inline float exp2_fast(float x) {
#if __has_builtin(__builtin_amdgcn_exp2f)
  return __builtin_amdgcn_exp2f(x);
#else
  return exp2f(x);
#endif
}

// ============================================================
// Kernel 1 (prep): blocks 0..999 per-superpoint tables; 1000..1014 weight swizzle.
// uT pre-scaled by LOG2E; W2 frags pre-scaled by LOG2E (exp->exp2 rebase).
// ============================================================
__global__ __launch_bounds__(256)
void k_prep(const float* __restrict__ sp_fea, const float* __restrict__ sp_xyz,
            const float* __restrict__ Wk, const float* __restrict__ bk,
            const float* __restrict__ Wv, const float* __restrict__ bv,
            const float* __restrict__ Wp1, const float* __restrict__ bp1,
            const float* __restrict__ gp, const float* __restrict__ betap,
            const float* __restrict__ mp, const float* __restrict__ vp,
            const float* __restrict__ Wp2, const float* __restrict__ bp2,
            const float* __restrict__ g1, const float* __restrict__ beta1,
            const float* __restrict__ m1, const float* __restrict__ v1,
            const float* __restrict__ bq,
            const float* __restrict__ Wq, const float* __restrict__ W1,
            const float* __restrict__ W2,
            const float* __restrict__ g2, const float* __restrict__ v2,
            const float* __restrict__ b1, const float* __restrict__ m2,
            const float* __restrict__ beta2, char* __restrict__ ws)
{
  if (blockIdx.x < 1000) {
    unsigned short* kp2h = (unsigned short*)(ws + KP2H_OFF);
    float* uT = (float*)(ws + UT_OFF);
    const int m = blockIdx.x;
    const int t = threadIdx.x;
    const int c = t & 127, half = t >> 7;
    __shared__ float fea[128];
    __shared__ float pk[128], pv[128];
    if (t < 128) fea[t] = sp_fea[m * 128 + t];
    __syncthreads();
    float kv = 0.f, vv = 0.f;
    const float* wkc = Wk + half * 64 * 128 + c;
    const float* wvc = Wv + half * 64 * 128 + c;
    const float* feah = fea + half * 64;
    #pragma unroll 8
    for (int d = 0; d < 64; ++d) {
      const float f = feah[d];
      kv = fmaf(f, wkc[d * 128], kv);
      vv = fmaf(f, wvc[d * 128], vv);
    }
    if (half) { pk[c] = kv; pv[c] = vv; }
    __syncthreads();
    if (!half) {
      kv += pk[c] + bk[c];
      vv += pv[c] + bv[c];
      const float x0 = sp_xyz[m*3+0], x1 = sp_xyz[m*3+1], x2 = sp_xyz[m*3+2];
      float pe = bp2[c];
      #pragma unroll
      for (int ii = 0; ii < 3; ++ii) {
        float s = bp1[ii] + x0*Wp1[0*3+ii] + x1*Wp1[1*3+ii] + x2*Wp1[2*3+ii];
        s = (s - mp[ii]) * (gp[ii] * rsqrtf(vp[ii] + EPS)) + betap[ii];
        s = fmaxf(s, 0.0f);
        pe += s * Wp2[ii*128 + c];
      }
      const float s1c = g1[c] * rsqrtf(v1[c] + EPS);
      const float kpv = (kv + pe - m1[c] - bq[c]) * s1c + beta1[c];
      kp2h[m*128 + c] = (unsigned short)(pk_bf16(kpv, kpv) & 0xFFFFu);
      pv[c] = vv + pe;          // reuse pv as (v+pe) storage
    }
    __syncthreads();
    if (t < 64) uT[m*64 + t] = (pv[t] + pv[t + 64]) * LOG2E;
  } else {
    const int tid = (blockIdx.x - 1000) * 256 + threadIdx.x;
    if (tid < 2048) {
      // Wqf^T A-frags: frag f = kt*8+mt ; A[m=c][k=d], Wqf[d][c]=Wq[d][c]*s1c[c]
      const int e = tid, f = e >> 6, l = e & 63;
      const int kt = f >> 3, mt = f & 7;
      const int c = mt*16 + (l & 15);
      const int d0 = kt*32 + (l >> 4)*8;
      const float sc = g1[c] * rsqrtf(v1[c] + EPS);
      uint4 u;
      u.x = pk_bf16(Wq[(d0+0)*128 + c]*sc, Wq[(d0+1)*128 + c]*sc);
      u.y = pk_bf16(Wq[(d0+2)*128 + c]*sc, Wq[(d0+3)*128 + c]*sc);
      u.z = pk_bf16(Wq[(d0+4)*128 + c]*sc, Wq[(d0+5)*128 + c]*sc);
      u.w = pk_bf16(Wq[(d0+6)*128 + c]*sc, Wq[(d0+7)*128 + c]*sc);
      *(uint4*)(ws + WQF_OFF + e*16) = u;
    } else if (tid < 3072) {
      // W1f^T A-frags: frag f = kt*4+jt ; A[m=j][k=c], W1f[c][j]=W1[c][j]*s2c[j]
      const int e = tid - 2048, f = e >> 6, l = e & 63;
      const int kt = f >> 2, jt = f & 3;
      const int j = jt*16 + (l & 15);
      const int c0 = kt*32 + (l >> 4)*8;
      const float sc = g2[j] * rsqrtf(v2[j] + EPS);
      uint4 u;
      u.x = pk_bf16(W1[(c0+0)*64 + j]*sc, W1[(c0+1)*64 + j]*sc);
      u.y = pk_bf16(W1[(c0+2)*64 + j]*sc, W1[(c0+3)*64 + j]*sc);
      u.z = pk_bf16(W1[(c0+4)*64 + j]*sc, W1[(c0+5)*64 + j]*sc);
      u.w = pk_bf16(W1[(c0+6)*64 + j]*sc, W1[(c0+7)*64 + j]*sc);
      *(uint4*)(ws + W1F_OFF + e*16) = u;
    } else if (tid < 3584) {
      // W2 B-frags scaled by LOG2E: frag f = kt2*4+nt ; B[k=j][n=j']
      const int e = tid - 3072, f = e >> 6, l = e & 63;
      const int kt2 = f >> 2, nt = f & 3;
      const int jp = nt*16 + (l & 15);
      const int j0 = kt2*32 + (l >> 4)*8;
      uint4 u;
      u.x = pk_bf16(W2[(j0+0)*64 + jp]*LOG2E, W2[(j0+1)*64 + jp]*LOG2E);
      u.y = pk_bf16(W2[(j0+2)*64 + jp]*LOG2E, W2[(j0+3)*64 + jp]*LOG2E);
      u.z = pk_bf16(W2[(j0+4)*64 + jp]*LOG2E, W2[(j0+5)*64 + jp]*LOG2E);
      u.w = pk_bf16(W2[(j0+6)*64 + jp]*LOG2E, W2[(j0+7)*64 + jp]*LOG2E);
      *(uint4*)(ws + W2F_OFF + e*16) = u;
    } else if (tid < 3648) {
      const int j = tid - 3584;
      const float sc = g2[j] * rsqrtf(v2[j] + EPS);
      ((float*)(ws + C1_OFF))[j] = (b1[j] - m2[j]) * sc + beta2[j];
    }
  }
}

// ============================================================
// Kernel 2: streaming q-projection (grid 1250, Wqf in LDS).
// ============================================================
__global__ __launch_bounds__(256, 4)
void k_q(const float* __restrict__ o_p_fea, char* __restrict__ ws)
{
  __shared__ __align__(16) char ldsq[32*1024];
  char* qs_g = ws + QSG_OFF;
  const int t = threadIdx.x;
  const int wave = t >> 6, l = t & 63;
  const int quad = l >> 4, row = l & 15;
  const int n0 = (blockIdx.x * 4 + wave) * 16;

  {
    const uint4* src = (const uint4*)(ws + WQF_OFF);
    uint4* dst = (uint4*)ldsq;
    #pragma unroll
    for (int i = 0; i < 8; ++i) dst[t + i*256] = src[t + i*256];
  }
  __syncthreads();

  f32x4 qa[8];
  #pragma unroll
  for (int mt = 0; mt < 8; ++mt) qa[mt] = (f32x4){0.f, 0.f, 0.f, 0.f};
  const float* feab = o_p_fea + (size_t)(n0 + row) * 128;
  #pragma unroll
  for (int kt = 0; kt < 4; ++kt) {
    f32x4 fa = *(const f32x4*)(feab + kt*32 + quad*8);
    f32x4 fb = *(const f32x4*)(feab + kt*32 + quad*8 + 4);
    FragU bu;
    bu.u[0] = pk_bf16(fa[0], fa[1]);
    bu.u[1] = pk_bf16(fa[2], fa[3]);
    bu.u[2] = pk_bf16(fb[0], fb[1]);
    bu.u[3] = pk_bf16(fb[2], fb[3]);
    #pragma unroll
    for (int mt = 0; mt < 8; ++mt) {
      const bf16x8 wf = *(const bf16x8*)(ldsq + ((kt*8+mt)*64 + l)*16);
      qa[mt] = __builtin_amdgcn_mfma_f32_16x16x32_bf16(wf, bu.v, qa[mt], 0, 0, 0);
    }
  }
  #pragma unroll
  for (int mt = 0; mt < 8; ++mt) {
    uint2 pp;
    pp.x = pk_bf16(qa[mt][0], qa[mt][1]);
    pp.y = pk_bf16(qa[mt][2], qa[mt][3]);
    *(uint2*)(qs_g + (size_t)(n0 + row) * 256 + mt*32 + quad*8) = pp;
  }
}

// ============================================================
// Kernel 3: fused main == r10 body EXACTLY (best measured k_main: 57 us,
// 84 VGPR, no spill), with BLOCK=512 (8 waves share one 24.8 KB weight
// stage). LDS/block = 24832 + 8*2304 = 43264 -> 3 blocks/CU x 8 waves =
// 24 waves/CU static (r10: 16), exactly matching the VGPR ceiling
// (512/84 -> 6 waves/SIMD). Grid 1250 x 8 waves x 4 group-tasks = 40000.
// EPILOGUE-PIPELINE VERDICT (r6/r11/r12): dead -- compiler pins ~84 VGPR
// regardless of launch_bounds/waves_per_eu and spills the state. Do not
// retry register-hungry pipelining on this body.
// ============================================================
#define H2_PITCH 144               // bytes/row (72 bf16; 16B-aligned rows)
#define H2_SIZE  (16*144)          // 2304 B / wave
#define W1L_OFF  0
#define W2L_OFF  (16*1024)
#define C1L_OFF  (24*1024)
#define H2_BASE  24832
#define LDS_TOTAL (H2_BASE + 8*H2_SIZE)   // 43264 (block=512: 8 waves)

__global__ __launch_bounds__(512, 3)
void k_main(const int* __restrict__ idx, const float* __restrict__ b2,
            const char* __restrict__ ws, float* __restrict__ out)
{
  const unsigned short* kp2h = (const unsigned short*)(ws + KP2H_OFF);
  const float* uT = (const float*)(ws + UT_OFF);
  const char* qs_g = ws + QSG_OFF;

  __shared__ __align__(16) char lds[LDS_TOTAL];
  const int t = threadIdx.x;            // 0..511
  const int wave = t >> 6, l = t & 63;  // 8 waves
  const int quad = l >> 4, row = l & 15;
  char* h2_w = lds + H2_BASE + wave * H2_SIZE;

  const int slot = blockIdx.x * 8 + wave;   // 0..9999 wave-slots
  const int gid0 = slot * 4;                // 4 group-tasks per wave
  const int nloc = row >> 3;

  // ---- stage weight fragments into block-shared LDS (24832 B) ----
  {
    const uint4* src = (const uint4*)(ws + W1F_OFF);
    uint4* dst = (uint4*)lds;
    #pragma unroll
    for (int i = 0; i < 4; ++i) {
      const int e = t + i * 512;
      if (e < WSTAGE_BYTES / 16) dst[e] = src[e];
    }
  }

  // prefetch this wave's 4 groups' gather indices (row pattern for kp2h)
  int mr4[4];
  #pragma unroll
  for (int g = 0; g < 4; ++g) mr4[g] = idx[(gid0 + g)*16 + row];

  __syncthreads();   // weights staged

  f32x4 c1r[4];
  #pragma unroll
  for (int jt = 0; jt < 4; ++jt)
    c1r[jt] = *(const f32x4*)(lds + C1L_OFF + (jt*16 + quad*4)*4);
  float b2r[4];
  #pragma unroll
  for (int nt = 0; nt < 4; ++nt) b2r[nt] = b2[row + nt*16] * LOG2E;

  // ---- group-0 staging: idx (quad pattern), kp2h row, qs row ----
  int msc[4];
  #pragma unroll
  for (int rg = 0; rg < 4; ++rg) msc[rg] = idx[gid0*16 + quad*4 + rg];
  uint4 kfc[4], qpc[4];
  {
    const uint4* kr = (const uint4*)(kp2h + (size_t)mr4[0] * 128);
    const uint4* qr = (const uint4*)(qs_g + (size_t)(gid0*2 + nloc) * 256);
    #pragma unroll
    for (int kt = 0; kt < 4; ++kt) { kfc[kt] = kr[kt*4 + quad]; qpc[kt] = qr[kt*4 + quad]; }
  }

  #pragma unroll 1
  for (int g = 0; g < 4; ++g) {
    const int gid = gid0 + g;
    // prefetch next group's operands (address-known; land during compute)
    int msn[4];
    uint4 kfn[4], qpn[4];
    if (g < 3) {
      #pragma unroll
      for (int rg = 0; rg < 4; ++rg) msn[rg] = idx[(gid+1)*16 + quad*4 + rg];
      const uint4* kr = (const uint4*)(kp2h + (size_t)mr4[g+1] * 128);
      const uint4* qr = (const uint4*)(qs_g + (size_t)((gid+1)*2 + nloc) * 256);
      #pragma unroll
      for (int kt = 0; kt < 4; ++kt) { kfn[kt] = kr[kt*4 + quad]; qpn[kt] = qr[kt*4 + quad]; }
    }
    // uT loads for THIS group; consumed after softmax
    float u4[4][4];
    #pragma unroll
    for (int rg = 0; rg < 4; ++rg) {
      const float* ur = uT + (size_t)msc[rg] * 64 + row;
      #pragma unroll
      for (int nt = 0; nt < 4; ++nt) u4[rg][nt] = ur[nt*16];
    }

    // GEMM1 (transposed): h2^T = W1f^T @ X^T ; X = relu(kp2[m] - qs[n])
    f32x4 a1[4];
    #pragma unroll
    for (int jt = 0; jt < 4; ++jt) a1[jt] = (f32x4){0.f, 0.f, 0.f, 0.f};
    #pragma unroll
    for (int kt = 0; kt < 4; ++kt) {
      const bf16v8 kv = __builtin_bit_cast(bf16v8, kfc[kt]);
      const bf16v8 qv = __builtin_bit_cast(bf16v8, qpc[kt]);
      bf16v8 z = {};
      bf16v8 x = __builtin_elementwise_max((bf16v8)(kv - qv), z);
      FragU xf;
      xf.q = __builtin_bit_cast(uint4, x);
      #pragma unroll
      for (int jt = 0; jt < 4; ++jt) {
        const bf16x8 wf = *(const bf16x8*)(lds + W1L_OFF + (kt*4+jt)*1024 + l*16);
        a1[jt] = __builtin_amdgcn_mfma_f32_16x16x32_bf16(wf, xf.v, a1[jt], 0, 0, 0);
      }
    }

    // bn2-fold + pack + packed relu; D^T: n=row -> r, m=quad*4+reg+16*jt -> j
    #pragma unroll
    for (int jt = 0; jt < 4; ++jt) {
      f32x4 v = a1[jt] + c1r[jt];
      uint2 pp;
      pp.x = pk_bf16(v[0], v[1]);
      pp.y = pk_bf16(v[2], v[3]);
      bf16v4 h = __builtin_bit_cast(bf16v4, pp);
      bf16v4 z4 = {};
      h = __builtin_elementwise_max(h, z4);
      pp = __builtin_bit_cast(uint2, h);
      *(uint2*)(h2_w + row*H2_PITCH + (jt*16 + quad*4)*2) = pp;
    }

    // GEMM2: s2' = h2 @ (W2*LOG2E)
    f32x4 a2[4];
    #pragma unroll
    for (int nt = 0; nt < 4; ++nt) a2[nt] = (f32x4){0.f, 0.f, 0.f, 0.f};
    #pragma unroll
    for (int kt2 = 0; kt2 < 2; ++kt2) {
      const bf16x8 af = *(const bf16x8*)(h2_w + row*H2_PITCH + kt2*64 + quad*16);
      #pragma unroll
      for (int nt = 0; nt < 4; ++nt) {
        const bf16x8 wf = *(const bf16x8*)(lds + W2L_OFF + (kt2*4+nt)*1024 + l*16);
        a2[nt] = __builtin_amdgcn_mfma_f32_16x16x32_bf16(af, wf, a2[nt], 0, 0, 0);
      }
    }
    // softmax over 8 rows/point (exp2, pre-scaled)
    float e[4][4], rs[4];
    #pragma unroll
    for (int nt = 0; nt < 4; ++nt) {
      #pragma unroll
      for (int rg = 0; rg < 4; ++rg) e[nt][rg] = exp2_fast(a2[nt][rg] + b2r[nt]);
      float s = e[nt][0] + e[nt][1] + e[nt][2] + e[nt][3];
      s += __shfl_xor(s, 16);
      rs[nt] = __builtin_amdgcn_rcpf(s);
    }
    // bi[r'] = sum_j' w[r'][j'] * uT[m(r')][j']  (uT pre-scaled by LOG2E)
    float bi[4] = {0.f, 0.f, 0.f, 0.f};
    #pragma unroll
    for (int rg = 0; rg < 4; ++rg) {
      #pragma unroll
      for (int nt = 0; nt < 4; ++nt)
        bi[rg] = fmaf(e[nt][rg] * rs[nt], u4[rg][nt], bi[rg]);
    }
    #pragma unroll
    for (int rg = 0; rg < 4; ++rg) {
      float b = bi[rg];
      b += __shfl_xor(b, 1);
      b += __shfl_xor(b, 2);
      b += __shfl_xor(b, 4);
      b += __shfl_xor(b, 8);
      bi[rg] = b;
    }
    // final softmax over k: bi pre-scaled by LOG2E -> exp2 direct
    const float eb0 = exp2_fast(bi[0]), eb1 = exp2_fast(bi[1]);
    const float eb2 = exp2_fast(bi[2]), eb3 = exp2_fast(bi[3]);
    float sb = eb0 + eb1 + eb2 + eb3;
    sb += __shfl_xor(sb, 16);
    const float rsb = __builtin_amdgcn_rcpf(sb);
    if (row < 4) {
      const float vsel = row == 0 ? eb0 : row == 1 ? eb1 : row == 2 ? eb2 : eb3;
      out[gid*16 + quad*4 + row] = vsel * rsb;
    }
    // rotate staged operands
    if (g < 3) {
      #pragma unroll
      for (int rg = 0; rg < 4; ++rg) msc[rg] = msn[rg];
      #pragma unroll
      for (int kt = 0; kt < 4; ++kt) { kfc[kt] = kfn[kt]; qpc[kt] = qpn[kt]; }
    }
  }
}

// ============================================================
extern "C" void kernel_launch(void* const* d_in, const int* in_sizes, int n_in,
                              void* d_out, int out_size, void* d_ws, size_t ws_size,
                              hipStream_t stream)
{
  const float* sp_fea  = (const float*)d_in[0];
  const float* sp_xyz  = (const float*)d_in[1];
  const float* o_p_fea = (const float*)d_in[2];
  // d_in[3] p_xyz unused by reference
  const float* Wq    = (const float*)d_in[4];
  const float* bq    = (const float*)d_in[5];
  const float* Wk    = (const float*)d_in[6];
  const float* bk    = (const float*)d_in[7];
  const float* Wv    = (const float*)d_in[8];
  const float* bv    = (const float*)d_in[9];
  const float* Wp1   = (const float*)d_in[10];
  const float* bp1   = (const float*)d_in[11];
  const float* gp    = (const float*)d_in[12];
  const float* betap = (const float*)d_in[13];
  const float* mp    = (const float*)d_in[14];
  const float* vp    = (const float*)d_in[15];
  const float* Wp2   = (const float*)d_in[16];
  const float* bp2   = (const float*)d_in[17];
  const float* g1    = (const float*)d_in[18];
  const float* beta1 = (const float*)d_in[19];
  const float* m1    = (const float*)d_in[20];
  const float* v1    = (const float*)d_in[21];
  const float* W1    = (const float*)d_in[22];
  const float* b1    = (const float*)d_in[23];
  const float* g2    = (const float*)d_in[24];
  const float* beta2 = (const float*)d_in[25];
  const float* m2    = (const float*)d_in[26];
  const float* v2    = (const float*)d_in[27];
  const float* W2    = (const float*)d_in[28];
  const float* b2    = (const float*)d_in[29];
  const int* c2p_idx_abs = (const int*)d_in[30];
  // d_in[31..34] unused by reference

  char* ws = (char*)d_ws;
  float* out = (float*)d_out;

  hipLaunchKernelGGL(k_prep, dim3(1015), dim3(256), 0, stream,
                     sp_fea, sp_xyz, Wk, bk, Wv, bv, Wp1, bp1, gp, betap, mp, vp,
                     Wp2, bp2, g1, beta1, m1, v1, bq,
                     Wq, W1, W2, g2, v2, b1, m2, beta2, ws);
  hipLaunchKernelGGL(k_q, dim3(1250), dim3(256), 0, stream,
                     o_p_fea, ws);
  hipLaunchKernelGGL(k_main, dim3(1250), dim3(512), 0, stream,
                     c2p_idx_abs, b2, ws, out);
}

// Round 14
// 209.165 us; speedup vs baseline: 1.3481x; 1.0284x over previous
//
#include <hip/hip_runtime.h>
#include <stdint.h>

#define EPS 1e-5f
#define LOG2E 1.4426950408889634f

// ---------------- problem constants ----------------
#define NPTS 80000
#define CDIM 128
#define ODIM 64
#define KNBR 8
#define MSUP 1000

// ---------------- workspace layout (bytes) ----------------
#define KP2H_OFF 0                 // [1000][128] bf16 = 256 KB (BN1-folded k+pe table)
#define UT_OFF   (256*1024)        // [1000][64]  f32  = 256 KB (LOG2E-scaled, INTERLEAVED:
                                   //   uTi[m][row*4+nt] = u[m][row+nt*16] -> f32x4 loads)
#define WQF_OFF  (512*1024)        // 32 frags * 1KB = 32 KB (Wq*s1c, A-layout)
#define W1F_OFF  (544*1024)        // 16 frags * 1KB = 16 KB (W1*s2c, A-layout)
#define W2F_OFF  (560*1024)        // 8 frags * 1KB  = 8 KB  (W2*LOG2E, B-layout)
#define C1_OFF   (568*1024)        // [64] f32 ((b1-m2)*s2c + beta2)
#define QSG_OFF  (576*1024)        // [80000][128] bf16 = 20.48 MB (q projection)
#define WSTAGE_BYTES (16*1024 + 8*1024 + 256)   // 24832 (W1F..C1 contiguous blob)

typedef float f32x4 __attribute__((ext_vector_type(4)));
typedef short bf16x8 __attribute__((ext_vector_type(8)));
typedef __bf16 bf16v8 __attribute__((ext_vector_type(8)));
typedef __bf16 bf16v4 __attribute__((ext_vector_type(4)));

union FragU { bf16x8 v; unsigned u[4]; uint4 q; };

#if __has_builtin(__builtin_amdgcn_cvt_pk_bf16_f32)
#define HAVE_PK_BF16 1
#endif

__device__ inline unsigned pk_bf16(float lo, float hi) {
#ifdef HAVE_PK_BF16
  typedef __bf16 bf16x2_t __attribute__((ext_vector_type(2)));
  return __builtin_bit_cast(unsigned, __builtin_amdgcn_cvt_pk_bf16_f32(lo, hi));
#else
  unsigned a = __builtin_bit_cast(unsigned, lo);
  unsigned b = __builtin_bit_cast(unsigned, hi);
  a += 0x7FFFu + ((a >> 16) & 1u);
  b += 0x7FFFu + ((b >> 16) & 1u);
  return (a >> 16) | (b & 0xFFFF0000u);
#endif
}

__device__ inline float exp2_fast(float x) {
#if __has_builtin(__builtin_amdgcn_exp2f)
  return __builtin_amdgcn_exp2f(x);
#else
  return exp2f(x);
#endif
}

// ============================================================
// Kernel 1 (prep): blocks 0..999 per-superpoint tables; 1000..1014 weight swizzle.
// uT stored INTERLEAVED + LOG2E-scaled; W2 frags pre-scaled by LOG2E.
// ============================================================
__global__ __launch_bounds__(256)
void k_prep(const float* __restrict__ sp_fea, const float* __restrict__ sp_xyz,
            const float* __restrict__ Wk, const float* __restrict__ bk,
            const float* __restrict__ Wv, const float* __restrict__ bv,
            const float* __restrict__ Wp1, const float* __restrict__ bp1,
            const float* __restrict__ gp, const float* __restrict__ betap,
            const float* __restrict__ mp, const float* __restrict__ vp,
            const float* __restrict__ Wp2, const float* __restrict__ bp2,
            const float* __restrict__ g1, const float* __restrict__ beta1,
            const float* __restrict__ m1, const float* __restrict__ v1,
            const float* __restrict__ bq,
            const float* __restrict__ Wq, const float* __restrict__ W1,
            const float* __restrict__ W2,
            const float* __restrict__ g2, const float* __restrict__ v2,
            const float* __restrict__ b1, const float* __restrict__ m2,
            const float* __restrict__ beta2, char* __restrict__ ws)
{
  if (blockIdx.x < 1000) {
    unsigned short* kp2h = (unsigned short*)(ws + KP2H_OFF);
    float* uT = (float*)(ws + UT_OFF);
    const int m = blockIdx.x;
    const int t = threadIdx.x;
    const int c = t & 127, half = t >> 7;
    __shared__ float fea[128];
    __shared__ float pk[128], pv[128];
    if (t < 128) fea[t] = sp_fea[m * 128 + t];
    __syncthreads();
    float kv = 0.f, vv = 0.f;
    const float* wkc = Wk + half * 64 * 128 + c;
    const float* wvc = Wv + half * 64 * 128 + c;
    const float* feah = fea + half * 64;
    #pragma unroll 8
    for (int d = 0; d < 64; ++d) {
      const float f = feah[d];
      kv = fmaf(f, wkc[d * 128], kv);
      vv = fmaf(f, wvc[d * 128], vv);
    }
    if (half) { pk[c] = kv; pv[c] = vv; }
    __syncthreads();
    if (!half) {
      kv += pk[c] + bk[c];
      vv += pv[c] + bv[c];
      const float x0 = sp_xyz[m*3+0], x1 = sp_xyz[m*3+1], x2 = sp_xyz[m*3+2];
      float pe = bp2[c];
      #pragma unroll
      for (int ii = 0; ii < 3; ++ii) {
        float s = bp1[ii] + x0*Wp1[0*3+ii] + x1*Wp1[1*3+ii] + x2*Wp1[2*3+ii];
        s = (s - mp[ii]) * (gp[ii] * rsqrtf(vp[ii] + EPS)) + betap[ii];
        s = fmaxf(s, 0.0f);
        pe += s * Wp2[ii*128 + c];
      }
      const float s1c = g1[c] * rsqrtf(v1[c] + EPS);
      const float kpv = (kv + pe - m1[c] - bq[c]) * s1c + beta1[c];
      kp2h[m*128 + c] = (unsigned short)(pk_bf16(kpv, kpv) & 0xFFFFu);
      pv[c] = vv + pe;          // reuse pv as (v+pe) storage
    }
    __syncthreads();
    // interleaved store: uTi[m][t] with t=row*4+nt holds u[m][row + nt*16]
    if (t < 64) {
      const int j = (t >> 2) + (t & 3) * 16;
      uT[m*64 + t] = (pv[j] + pv[j + 64]) * LOG2E;
    }
  } else {
    const int tid = (blockIdx.x - 1000) * 256 + threadIdx.x;
    if (tid < 2048) {
      // Wqf^T A-frags: frag f = kt*8+mt ; A[m=c][k=d], Wqf[d][c]=Wq[d][c]*s1c[c]
      const int e = tid, f = e >> 6, l = e & 63;
      const int kt = f >> 3, mt = f & 7;
      const int c = mt*16 + (l & 15);
      const int d0 = kt*32 + (l >> 4)*8;
      const float sc = g1[c] * rsqrtf(v1[c] + EPS);
      uint4 u;
      u.x = pk_bf16(Wq[(d0+0)*128 + c]*sc, Wq[(d0+1)*128 + c]*sc);
      u.y = pk_bf16(Wq[(d0+2)*128 + c]*sc, Wq[(d0+3)*128 + c]*sc);
      u.z = pk_bf16(Wq[(d0+4)*128 + c]*sc, Wq[(d0+5)*128 + c]*sc);
      u.w = pk_bf16(Wq[(d0+6)*128 + c]*sc, Wq[(d0+7)*128 + c]*sc);
      *(uint4*)(ws + WQF_OFF + e*16) = u;
    } else if (tid < 3072) {
      // W1f^T A-frags: frag f = kt*4+jt ; A[m=j][k=c], W1f[c][j]=W1[c][j]*s2c[j]
      const int e = tid - 2048, f = e >> 6, l = e & 63;
      const int kt = f >> 2, jt = f & 3;
      const int j = jt*16 + (l & 15);
      const int c0 = kt*32 + (l >> 4)*8;
      const float sc = g2[j] * rsqrtf(v2[j] + EPS);
      uint4 u;
      u.x = pk_bf16(W1[(c0+0)*64 + j]*sc, W1[(c0+1)*64 + j]*sc);
      u.y = pk_bf16(W1[(c0+2)*64 + j]*sc, W1[(c0+3)*64 + j]*sc);
      u.z = pk_bf16(W1[(c0+4)*64 + j]*sc, W1[(c0+5)*64 + j]*sc);
      u.w = pk_bf16(W1[(c0+6)*64 + j]*sc, W1[(c0+7)*64 + j]*sc);
      *(uint4*)(ws + W1F_OFF + e*16) = u;
    } else if (tid < 3584) {
      // W2 B-frags scaled by LOG2E: frag f = kt2*4+nt ; B[k=j][n=j']
      const int e = tid - 3072, f = e >> 6, l = e & 63;
      const int kt2 = f >> 2, nt = f & 3;
      const int jp = nt*16 + (l & 15);
      const int j0 = kt2*32 + (l >> 4)*8;
      uint4 u;
      u.x = pk_bf16(W2[(j0+0)*64 + jp]*LOG2E, W2[(j0+1)*64 + jp]*LOG2E);
      u.y = pk_bf16(W2[(j0+2)*64 + jp]*LOG2E, W2[(j0+3)*64 + jp]*LOG2E);
      u.z = pk_bf16(W2[(j0+4)*64 + jp]*LOG2E, W2[(j0+5)*64 + jp]*LOG2E);
      u.w = pk_bf16(W2[(j0+6)*64 + jp]*LOG2E, W2[(j0+7)*64 + jp]*LOG2E);
      *(uint4*)(ws + W2F_OFF + e*16) = u;
    } else if (tid < 3648) {
      const int j = tid - 3584;
      const float sc = g2[j] * rsqrtf(v2[j] + EPS);
      ((float*)(ws + C1_OFF))[j] = (b1[j] - m2[j]) * sc + beta2[j];
    }
  }
}

// ============================================================
// Kernel 2: streaming q-projection (grid 1250, Wqf in LDS).
// ============================================================
__global__ __launch_bounds__(256, 4)
void k_q(const float* __restrict__ o_p_fea, char* __restrict__ ws)
{
  __shared__ __align__(16) char ldsq[32*1024];
  char* qs_g = ws + QSG_OFF;
  const int t = threadIdx.x;
  const int wave = t >> 6, l = t & 63;
  const int quad = l >> 4, row = l & 15;
  const int n0 = (blockIdx.x * 4 + wave) * 16;

  {
    const uint4* src = (const uint4*)(ws + WQF_OFF);
    uint4* dst = (uint4*)ldsq;
    #pragma unroll
    for (int i = 0; i < 8; ++i) dst[t + i*256] = src[t + i*256];
  }
  __syncthreads();

  f32x4 qa[8];
  #pragma unroll
  for (int mt = 0; mt < 8; ++mt) qa[mt] = (f32x4){0.f, 0.f, 0.f, 0.f};
  const float* feab = o_p_fea + (size_t)(n0 + row) * 128;
  #pragma unroll
  for (int kt = 0; kt < 4; ++kt) {
    f32x4 fa = *(const f32x4*)(feab + kt*32 + quad*8);
    f32x4 fb = *(const f32x4*)(feab + kt*32 + quad*8 + 4);
    FragU bu;
    bu.u[0] = pk_bf16(fa[0], fa[1]);
    bu.u[1] = pk_bf16(fa[2], fa[3]);
    bu.u[2] = pk_bf16(fb[0], fb[1]);
    bu.u[3] = pk_bf16(fb[2], fb[3]);
    #pragma unroll
    for (int mt = 0; mt < 8; ++mt) {
      const bf16x8 wf = *(const bf16x8*)(ldsq + ((kt*8+mt)*64 + l)*16);
      qa[mt] = __builtin_amdgcn_mfma_f32_16x16x32_bf16(wf, bu.v, qa[mt], 0, 0, 0);
    }
  }
  #pragma unroll
  for (int mt = 0; mt < 8; ++mt) {
    uint2 pp;
    pp.x = pk_bf16(qa[mt][0], qa[mt][1]);
    pp.y = pk_bf16(qa[mt][2], qa[mt][3]);
    *(uint2*)(qs_g + (size_t)(n0 + row) * 256 + mt*32 + quad*8) = pp;
  }
}

// ============================================================
// Kernel 3: fused main == r10 EXACTLY (best measured: 57 us, block 256,
// grid 2500, 84 VGPR, no spill) + interleaved-uT gather: the old
// 16-scalar-dword uT gather per group is now 4 coalesced f32x4 loads
// (within a quad all 16 lanes share m -> one contiguous 256 B row).
// CONFIG-SPACE VERDICTS: geometry optimum = block256/grid2500 (r8, r13
// regressed); epilogue pipelining dead (r6/r11/r12: compiler pins 84 VGPR
// and spills); VALU micro-cuts neutral (r7/r9).
// ============================================================
#define H2_PITCH 144               // bytes/row (72 bf16; 16B-aligned rows)
#define H2_SIZE  (16*144)          // 2304 B / wave
#define W1L_OFF  0
#define W2L_OFF  (16*1024)
#define C1L_OFF  (24*1024)
#define H2_BASE  24832
#define LDS_TOTAL (H2_BASE + 4*H2_SIZE)   // 34048

__global__ __launch_bounds__(256, 3)
void k_main(const int* __restrict__ idx, const float* __restrict__ b2,
            const char* __restrict__ ws, float* __restrict__ out)
{
  const unsigned short* kp2h = (const unsigned short*)(ws + KP2H_OFF);
  const float* uT = (const float*)(ws + UT_OFF);
  const char* qs_g = ws + QSG_OFF;

  __shared__ __align__(16) char lds[LDS_TOTAL];
  const int t = threadIdx.x;
  const int wave = t >> 6, l = t & 63;
  const int quad = l >> 4, row = l & 15;
  char* h2_w = lds + H2_BASE + wave * H2_SIZE;

  const int slot = blockIdx.x * 4 + wave;   // 0..9999 wave-slots
  const int gid0 = slot * 4;                // 4 group-tasks per wave
  const int nloc = row >> 3;

  // ---- stage weight fragments into block-shared LDS (24832 B) ----
  {
    const uint4* src = (const uint4*)(ws + W1F_OFF);
    uint4* dst = (uint4*)lds;
    #pragma unroll
    for (int i = 0; i < 7; ++i) {
      const int e = t + i * 256;
      if (e < WSTAGE_BYTES / 16) dst[e] = src[e];
    }
  }

  // prefetch this wave's 4 groups' gather indices (row pattern for kp2h)
  int mr4[4];
  #pragma unroll
  for (int g = 0; g < 4; ++g) mr4[g] = idx[(gid0 + g)*16 + row];

  __syncthreads();   // weights staged

  f32x4 c1r[4];
  #pragma unroll
  for (int jt = 0; jt < 4; ++jt)
    c1r[jt] = *(const f32x4*)(lds + C1L_OFF + (jt*16 + quad*4)*4);
  float b2r[4];
  #pragma unroll
  for (int nt = 0; nt < 4; ++nt) b2r[nt] = b2[row + nt*16] * LOG2E;

  // ---- group-0 staging: idx (quad pattern), kp2h row, qs row ----
  int msc[4];
  #pragma unroll
  for (int rg = 0; rg < 4; ++rg) msc[rg] = idx[gid0*16 + quad*4 + rg];
  uint4 kfc[4], qpc[4];
  {
    const uint4* kr = (const uint4*)(kp2h + (size_t)mr4[0] * 128);
    const uint4* qr = (const uint4*)(qs_g + (size_t)(gid0*2 + nloc) * 256);
    #pragma unroll
    for (int kt = 0; kt < 4; ++kt) { kfc[kt] = kr[kt*4 + quad]; qpc[kt] = qr[kt*4 + quad]; }
  }

  #pragma unroll 1
  for (int g = 0; g < 4; ++g) {
    const int gid = gid0 + g;
    // prefetch next group's operands (address-known; land during compute)
    int msn[4];
    uint4 kfn[4], qpn[4];
    if (g < 3) {
      #pragma unroll
      for (int rg = 0; rg < 4; ++rg) msn[rg] = idx[(gid+1)*16 + quad*4 + rg];
      const uint4* kr = (const uint4*)(kp2h + (size_t)mr4[g+1] * 128);
      const uint4* qr = (const uint4*)(qs_g + (size_t)((gid+1)*2 + nloc) * 256);
      #pragma unroll
      for (int kt = 0; kt < 4; ++kt) { kfn[kt] = kr[kt*4 + quad]; qpn[kt] = qr[kt*4 + quad]; }
    }
    // uT loads for THIS group: interleaved layout -> one f32x4 per rg
    // (u4[rg][nt] = u_orig[msc[rg]][row + nt*16])
    f32x4 u4[4];
    #pragma unroll
    for (int rg = 0; rg < 4; ++rg)
      u4[rg] = *(const f32x4*)(uT + (size_t)msc[rg] * 64 + row * 4);

    // GEMM1 (transposed): h2^T = W1f^T @ X^T ; X = relu(kp2[m] - qs[n])
    f32x4 a1[4];
    #pragma unroll
    for (int jt = 0; jt < 4; ++jt) a1[jt] = (f32x4){0.f, 0.f, 0.f, 0.f};
    #pragma unroll
    for (int kt = 0; kt < 4; ++kt) {
      const bf16v8 kv = __builtin_bit_cast(bf16v8, kfc[kt]);
      const bf16v8 qv = __builtin_bit_cast(bf16v8, qpc[kt]);
      bf16v8 z = {};
      bf16v8 x = __builtin_elementwise_max((bf16v8)(kv - qv), z);
      FragU xf;
      xf.q = __builtin_bit_cast(uint4, x);
      #pragma unroll
      for (int jt = 0; jt < 4; ++jt) {
        const bf16x8 wf = *(const bf16x8*)(lds + W1L_OFF + (kt*4+jt)*1024 + l*16);
        a1[jt] = __builtin_amdgcn_mfma_f32_16x16x32_bf16(wf, xf.v, a1[jt], 0, 0, 0);
      }
    }

    // bn2-fold + pack + packed relu; D^T: n=row -> r, m=quad*4+reg+16*jt -> j
    #pragma unroll
    for (int jt = 0; jt < 4; ++jt) {
      f32x4 v = a1[jt] + c1r[jt];
      uint2 pp;
      pp.x = pk_bf16(v[0], v[1]);
      pp.y = pk_bf16(v[2], v[3]);
      bf16v4 h = __builtin_bit_cast(bf16v4, pp);
      bf16v4 z4 = {};
      h = __builtin_elementwise_max(h, z4);
      pp = __builtin_bit_cast(uint2, h);
      *(uint2*)(h2_w + row*H2_PITCH + (jt*16 + quad*4)*2) = pp;
    }

    // GEMM2: s2' = h2 @ (W2*LOG2E)
    f32x4 a2[4];
    #pragma unroll
    for (int nt = 0; nt < 4; ++nt) a2[nt] = (f32x4){0.f, 0.f, 0.f, 0.f};
    #pragma unroll
    for (int kt2 = 0; kt2 < 2; ++kt2) {
      const bf16x8 af = *(const bf16x8*)(h2_w + row*H2_PITCH + kt2*64 + quad*16);
      #pragma unroll
      for (int nt = 0; nt < 4; ++nt) {
        const bf16x8 wf = *(const bf16x8*)(lds + W2L_OFF + (kt2*4+nt)*1024 + l*16);
        a2[nt] = __builtin_amdgcn_mfma_f32_16x16x32_bf16(af, wf, a2[nt], 0, 0, 0);
      }
    }
    // softmax over 8 rows/point (exp2, pre-scaled)
    float e[4][4], rs[4];
    #pragma unroll
    for (int nt = 0; nt < 4; ++nt) {
      #pragma unroll
      for (int rg = 0; rg < 4; ++rg) e[nt][rg] = exp2_fast(a2[nt][rg] + b2r[nt]);
      float s = e[nt][0] + e[nt][1] + e[nt][2] + e[nt][3];
      s += __shfl_xor(s, 16);
      rs[nt] = __builtin_amdgcn_rcpf(s);
    }
    // bi[r'] = sum_j' w[r'][j'] * u[m(r')][j']  (u pre-scaled by LOG2E)
    float bi[4] = {0.f, 0.f, 0.f, 0.f};
    #pragma unroll
    for (int rg = 0; rg < 4; ++rg) {
      #pragma unroll
      for (int nt = 0; nt < 4; ++nt)
        bi[rg] = fmaf(e[nt][rg] * rs[nt], u4[rg][nt], bi[rg]);
    }
    #pragma unroll
    for (int rg = 0; rg < 4; ++rg) {
      float b = bi[rg];
      b += __shfl_xor(b, 1);
      b += __shfl_xor(b, 2);
      b += __shfl_xor(b, 4);
      b += __shfl_xor(b, 8);
      bi[rg] = b;
    }
    // final softmax over k: bi pre-scaled by LOG2E -> exp2 direct
    const float eb0 = exp2_fast(bi[0]), eb1 = exp2_fast(bi[1]);
    const float eb2 = exp2_fast(bi[2]), eb3 = exp2_fast(bi[3]);
    float sb = eb0 + eb1 + eb2 + eb3;
    sb += __shfl_xor(sb, 16);
    const float rsb = __builtin_amdgcn_rcpf(sb);
    if (row < 4) {
      const float vsel = row == 0 ? eb0 : row == 1 ? eb1 : row == 2 ? eb2 : eb3;
      out[gid*16 + quad*4 + row] = vsel * rsb;
    }
    // rotate staged operands
    if (g < 3) {
      #pragma unroll
      for (int rg = 0; rg < 4; ++rg) msc[rg] = msn[rg];
      #pragma unroll
      for (int kt = 0; kt < 4; ++kt) { kfc[kt] = kfn[kt]; qpc[kt] = qpn[kt]; }
    }
  }
}

// ============================================================
extern "C" void kernel_launch(void* const* d_in, const int* in_sizes, int n_in,
                              void* d_out, int out_size, void* d_ws, size_t ws_size,
                              hipStream_t stream)
{
  const float* sp_fea  = (const float*)d_in[0];
  const float* sp_xyz  = (const float*)d_in[1];
  const float* o_p_fea = (const float*)d_in[2];
  // d_in[3] p_xyz unused by reference
  const float* Wq    = (const float*)d_in[4];
  const float* bq    = (const float*)d_in[5];
  const float* Wk    = (const float*)d_in[6];
  const float* bk    = (const float*)d_in[7];
  const float* Wv    = (const float*)d_in[8];
  const float* bv    = (const float*)d_in[9];
  const float* Wp1   = (const float*)d_in[10];
  const float* bp1   = (const float*)d_in[11];
  const float* gp    = (const float*)d_in[12];
  const float* betap = (const float*)d_in[13];
  const float* mp    = (const float*)d_in[14];
  const float* vp    = (const float*)d_in[15];
  const float* Wp2   = (const float*)d_in[16];
  const float* bp2   = (const float*)d_in[17];
  const float* g1    = (const float*)d_in[18];
  const float* beta1 = (const float*)d_in[19];
  const float* m1    = (const float*)d_in[20];
  const float* v1    = (const float*)d_in[21];
  const float* W1    = (const float*)d_in[22];
  const float* b1    = (const float*)d_in[23];
  const float* g2    = (const float*)d_in[24];
  const float* beta2 = (const float*)d_in[25];
  const float* m2    = (const float*)d_in[26];
  const float* v2    = (const float*)d_in[27];
  const float* W2    = (const float*)d_in[28];
  const float* b2    = (const float*)d_in[29];
  const int* c2p_idx_abs = (const int*)d_in[30];
  // d_in[31..34] unused by reference

  char* ws = (char*)d_ws;
  float* out = (float*)d_out;

  hipLaunchKernelGGL(k_prep, dim3(1015), dim3(256), 0, stream,
                     sp_fea, sp_xyz, Wk, bk, Wv, bv, Wp1, bp1, gp, betap, mp, vp,
                     Wp2, bp2, g1, beta1, m1, v1, bq,
                     Wq, W1, W2, g2, v2, b1, m2, beta2, ws);
  hipLaunchKernelGGL(k_q, dim3(1250), dim3(256), 0, stream,
                     o_p_fea, ws);
  hipLaunchKernelGGL(k_main, dim3(2500), dim3(256), 0, stream,
                     c2p_idx_abs, b2, ws, out);
}